// Round 1
// baseline (504.259 us; speedup 1.0000x reference)
//
#include <hip/hip_runtime.h>

#define DIM   64
#define NEMB  1024
#define HW    4096      // 64*64
#define NPIX  131072    // 32*64*64
#define NOUT  8388608   // 32*64*64*64

// ---------------------------------------------------------------------------
// prep: eT[j][d] = embed[d][j]  (transpose so code rows are contiguous for
// scalar loads), and cn[j] = sum_d embed[d][j]^2 computed with numpy's
// axis-0 semantics (separate rounded muls, sequential adds).
// ---------------------------------------------------------------------------
__global__ __launch_bounds__(256) void prep_kernel(const float* __restrict__ embed,
                                                   float* __restrict__ eT,
                                                   float* __restrict__ cn) {
    const int j = blockIdx.x * 256 + threadIdx.x;
    if (j >= NEMB) return;
    float v[DIM];
#pragma unroll
    for (int d = 0; d < DIM; ++d) {
        v[d] = embed[d * NEMB + j];      // coalesced across lanes (consecutive j)
        eT[j * DIM + d] = v[d];
    }
    float s = __fmul_rn(v[0], v[0]);
#pragma unroll
    for (int d = 1; d < DIM; ++d)
        s = __fadd_rn(s, __fmul_rn(v[d], v[d]));   // sequential, no contraction
    cn[j] = s;
}

// ---------------------------------------------------------------------------
// main: one pixel per thread. x[64] in VGPRs; code rows eT[j][*] are
// wave-uniform -> scalar (s_load) path. 4 independent FMA chains for ILP.
// dist computed exactly as the reference expression: (||f||^2 - 2*dot) + c_j.
// ---------------------------------------------------------------------------
__global__ __launch_bounds__(256) void vq_kernel(const float* __restrict__ X,
                                                 const float* __restrict__ embed,
                                                 const float* __restrict__ eT,
                                                 const float* __restrict__ cn,
                                                 float* __restrict__ OUT,
                                                 float* __restrict__ loss) {
    const int n = blockIdx.x * 256 + threadIdx.x;
    const int b = n >> 12;          // image index
    const int p = n & 4095;         // h*64+w within image
    const float* xb = X + (size_t)b * (DIM * HW) + p;

    float x[DIM];
#pragma unroll
    for (int d = 0; d < DIM; ++d) x[d] = xb[(size_t)d * HW];   // coalesced per d

    // ||f||^2 with numpy pairwise 8-accumulator pattern (n=64, no tail):
    // r[k] = x[k]^2 + x[k+8]^2 + ... ; result = ((r0+r1)+(r2+r3))+((r4+r5)+(r6+r7))
    float r[8];
#pragma unroll
    for (int k = 0; k < 8; ++k) r[k] = __fmul_rn(x[k], x[k]);
#pragma unroll
    for (int i = 8; i < DIM; i += 8)
#pragma unroll
        for (int k = 0; k < 8; ++k)
            r[k] = __fadd_rn(r[k], __fmul_rn(x[i + k], x[i + k]));
    const float ff = __fadd_rn(
        __fadd_rn(__fadd_rn(r[0], r[1]), __fadd_rn(r[2], r[3])),
        __fadd_rn(__fadd_rn(r[4], r[5]), __fadd_rn(r[6], r[7])));

    float minv = __builtin_inff();
    int   mini = 0;

#pragma unroll 1
    for (int j0 = 0; j0 < NEMB; j0 += 4) {
        const float* e = eT + (size_t)j0 * DIM;   // uniform address -> s_load
        float a0 = 0.f, a1 = 0.f, a2 = 0.f, a3 = 0.f;
#pragma unroll
        for (int d = 0; d < DIM; ++d) {
            const float xd = x[d];
            a0 = fmaf(xd, e[d],           a0);   // sequential-k FMA (BLAS order)
            a1 = fmaf(xd, e[DIM + d],     a1);
            a2 = fmaf(xd, e[2 * DIM + d], a2);
            a3 = fmaf(xd, e[3 * DIM + d], a3);
        }
        const float d0 = __fadd_rn(__fsub_rn(ff, __fmul_rn(2.f, a0)), cn[j0 + 0]);
        const float d1 = __fadd_rn(__fsub_rn(ff, __fmul_rn(2.f, a1)), cn[j0 + 1]);
        const float d2 = __fadd_rn(__fsub_rn(ff, __fmul_rn(2.f, a2)), cn[j0 + 2]);
        const float d3 = __fadd_rn(__fsub_rn(ff, __fmul_rn(2.f, a3)), cn[j0 + 3]);
        // strict < keeps first occurrence on ties, matching np.argmin
        if (d0 < minv) { minv = d0; mini = j0 + 0; }
        if (d1 < minv) { minv = d1; mini = j0 + 1; }
        if (d2 < minv) { minv = d2; mini = j0 + 2; }
        if (d3 < minv) { minv = d3; mini = j0 + 3; }
    }

    // epilogue: gather code, write q_out = x + (q - x) literally, accumulate MSE
    float lerr = 0.f;
    float* outb = OUT + (size_t)b * (DIM * HW) + p;
#pragma unroll
    for (int d = 0; d < DIM; ++d) {
        const float q  = embed[d * NEMB + mini];   // L2-resident gather (256 KB)
        const float df = __fsub_rn(q, x[d]);
        outb[(size_t)d * HW] = __fadd_rn(x[d], df);
        lerr = fmaf(df, df, lerr);
    }

    __shared__ float sred[256];
    sred[threadIdx.x] = lerr;
    __syncthreads();
#pragma unroll
    for (int s = 128; s > 0; s >>= 1) {
        if (threadIdx.x < s) sred[threadIdx.x] += sred[threadIdx.x + s];
        __syncthreads();
    }
    if (threadIdx.x == 0)
        atomicAdd(loss, sred[0] * (1.0f / (float)NOUT));
}

extern "C" void kernel_launch(void* const* d_in, const int* in_sizes, int n_in,
                              void* d_out, int out_size, void* d_ws, size_t ws_size,
                              hipStream_t stream) {
    const float* X = (const float*)d_in[0];
    const float* E = (const float*)d_in[1];
    float* eT  = (float*)d_ws;                 // 1024*64 floats
    float* cn  = eT + NEMB * DIM;              // 1024 floats
    float* OUT = (float*)d_out;
    float* loss = OUT + NOUT;                  // second output (scalar)

    hipMemsetAsync(loss, 0, sizeof(float), stream);   // atomic accumulator
    prep_kernel<<<NEMB / 256, 256, 0, stream>>>(E, eT, cn);
    vq_kernel<<<NPIX / 256, 256, 0, stream>>>(X, E, eT, cn, OUT, loss);
}